// Round 1
// baseline (2532.567 us; speedup 1.0000x reference)
//
#include <hip/hip_runtime.h>
#include <hip/hip_bf16.h>
#include <cstdint>
#include <cstddef>

#define N_NODES 100000
#define D 256
#define NPB 16   // nodes per block in GEMM kernels; 100000 % 16 == 0

// ---------------- CSR build ----------------

__global__ __launch_bounds__(256) void count_deg(const int* __restrict__ ei,
                                                 int* __restrict__ deg, int E) {
    int e = blockIdx.x * 256 + threadIdx.x;
    if (e < E) atomicAdd(&deg[ei[E + e]], 1);
}

__global__ __launch_bounds__(256) void deg_inv_k(const int* __restrict__ deg,
                                                 float* __restrict__ dinv, int N) {
    int i = blockIdx.x * 256 + threadIdx.x;
    if (i < N) dinv[i] = 1.0f / fmaxf((float)deg[i], 1.0f);
}

// per-block exclusive scan of deg -> rowstart (partial), block totals -> bsums
__global__ __launch_bounds__(256) void scan1(const int* __restrict__ deg,
                                             int* __restrict__ rowstart,
                                             int* __restrict__ bsums, int N) {
    __shared__ int s[256];
    int i = blockIdx.x * 256 + threadIdx.x;
    int v = (i < N) ? deg[i] : 0;
    s[threadIdx.x] = v;
    __syncthreads();
    for (int d = 1; d < 256; d <<= 1) {
        int t = (threadIdx.x >= d) ? s[threadIdx.x - d] : 0;
        __syncthreads();
        s[threadIdx.x] += t;
        __syncthreads();
    }
    if (i < N) rowstart[i] = s[threadIdx.x] - v;   // exclusive
    if (threadIdx.x == 255) bsums[blockIdx.x] = s[255];
}

__global__ void scan2(int* bsums, int nb) {
    if (threadIdx.x == 0 && blockIdx.x == 0) {
        int run = 0;
        for (int b = 0; b < nb; b++) { int t = bsums[b]; bsums[b] = run; run += t; }
    }
}

__global__ __launch_bounds__(256) void scan3(int* __restrict__ rowstart,
                                             const int* __restrict__ bsums, int N) {
    int i = blockIdx.x * 256 + threadIdx.x;
    if (i < N) rowstart[i] += bsums[blockIdx.x];
}

__global__ __launch_bounds__(256) void fill_csr(const int* __restrict__ ei,
                                                const int* __restrict__ rowstart,
                                                int* __restrict__ cursor,
                                                int* __restrict__ csr, int E) {
    int e = blockIdx.x * 256 + threadIdx.x;
    if (e < E) {
        int src = ei[e], dst = ei[E + e];
        int slot = atomicAdd(&cursor[dst], 1);
        csr[rowstart[dst] + slot] = src;
    }
}

// ---------------- aggregation: one wave per node, lane holds float4 of cols ----------------

__global__ __launch_bounds__(256) void agg_k(const float* __restrict__ X,
                                             const int* __restrict__ csr,
                                             const int* __restrict__ rowstart,
                                             const int* __restrict__ deg,
                                             float* __restrict__ out) {
    int node = blockIdx.x * 4 + (threadIdx.x >> 6);
    int lane = threadIdx.x & 63;
    int start = rowstart[node];
    int cnt = deg[node];
    float4 acc = make_float4(0.f, 0.f, 0.f, 0.f);
    int j = 0;
    for (; j + 4 <= cnt; j += 4) {
        int s0 = csr[start + j + 0];
        int s1 = csr[start + j + 1];
        int s2 = csr[start + j + 2];
        int s3 = csr[start + j + 3];
        float4 v0 = *(const float4*)(X + (size_t)s0 * D + lane * 4);
        float4 v1 = *(const float4*)(X + (size_t)s1 * D + lane * 4);
        float4 v2 = *(const float4*)(X + (size_t)s2 * D + lane * 4);
        float4 v3 = *(const float4*)(X + (size_t)s3 * D + lane * 4);
        acc.x += v0.x + v1.x + v2.x + v3.x;
        acc.y += v0.y + v1.y + v2.y + v3.y;
        acc.z += v0.z + v1.z + v2.z + v3.z;
        acc.w += v0.w + v1.w + v2.w + v3.w;
    }
    for (; j < cnt; j++) {
        int s0 = csr[start + j];
        float4 v0 = *(const float4*)(X + (size_t)s0 * D + lane * 4);
        acc.x += v0.x; acc.y += v0.y; acc.z += v0.z; acc.w += v0.w;
    }
    *(float4*)(out + (size_t)node * D + lane * 4) = acc;   // raw sum; dinv applied in GEMM
}

// ---------------- fused SAGE conv: out = relu(agg*dinv @ Wl + X @ Wr + b) ----------------
// 256 threads = 256 output cols; NPB nodes per block. A-operand reads are
// wave-uniform (scalar loads on SMEM pipe); W streamed from L2, reused NPB x.

__global__ __launch_bounds__(256) void conv_k(const float* __restrict__ Araw,
                                              const float* __restrict__ dinv,
                                              const float* __restrict__ X,
                                              const float* __restrict__ Wl,
                                              const float* __restrict__ Wr,
                                              const float* __restrict__ bias,
                                              float* __restrict__ out) {
    int col = threadIdx.x;
    int node0 = blockIdx.x * NPB;
    const float* a0 = Araw + (size_t)node0 * D;
    const float* x0 = X + (size_t)node0 * D;
    float accm[NPB], accx[NPB];
#pragma unroll
    for (int i = 0; i < NPB; i++) { accm[i] = 0.f; accx[i] = 0.f; }
#pragma unroll 4
    for (int k = 0; k < D; k++) {
        float wl = Wl[k * D + col];
        float wr = Wr[k * D + col];
#pragma unroll
        for (int i = 0; i < NPB; i++) {
            accm[i] = fmaf(a0[(size_t)i * D + k], wl, accm[i]);
            accx[i] = fmaf(x0[(size_t)i * D + k], wr, accx[i]);
        }
    }
    // all reads of this block's A rows are complete for ALL threads before any
    // write: required because conv2 writes its output in place over Araw.
    __syncthreads();
    float b = bias[col];
#pragma unroll
    for (int i = 0; i < NPB; i++) {
        float r = fmaf(accm[i], dinv[node0 + i], accx[i]) + b;
        r = fmaxf(r, 0.f);
        out[(size_t)(node0 + i) * D + col] = r;
    }
}

// ---------------- final linear: out = A @ W + b ----------------

__global__ __launch_bounds__(256) void lin_k(const float* __restrict__ A,
                                             const float* __restrict__ W,
                                             const float* __restrict__ bias,
                                             float* __restrict__ out) {
    int col = threadIdx.x;
    int node0 = blockIdx.x * NPB;
    const float* a0 = A + (size_t)node0 * D;
    float acc[NPB];
#pragma unroll
    for (int i = 0; i < NPB; i++) acc[i] = 0.f;
#pragma unroll 4
    for (int k = 0; k < D; k++) {
        float w = W[k * D + col];
#pragma unroll
        for (int i = 0; i < NPB; i++)
            acc[i] = fmaf(a0[(size_t)i * D + k], w, acc[i]);
    }
    float b = bias[col];
#pragma unroll
    for (int i = 0; i < NPB; i++)
        out[(size_t)(node0 + i) * D + col] = acc[i] + b;
}

// ---------------- launch ----------------

extern "C" void kernel_launch(void* const* d_in, const int* in_sizes, int n_in,
                              void* d_out, int out_size, void* d_ws, size_t ws_size,
                              hipStream_t stream) {
    const float* x   = (const float*)d_in[0];
    const int*   ei  = (const int*)d_in[1];
    const float* W1l = (const float*)d_in[2];
    const float* b1  = (const float*)d_in[3];
    const float* W1r = (const float*)d_in[4];
    const float* W2l = (const float*)d_in[5];
    const float* b2  = (const float*)d_in[6];
    const float* W2r = (const float*)d_in[7];
    const float* W3  = (const float*)d_in[8];
    const float* b3  = (const float*)d_in[9];
    float* out = (float*)d_out;

    const int N = N_NODES;
    const int E = in_sizes[1] / 2;

    char* p = (char*)d_ws;
    float* agg  = (float*)p; p += (size_t)N * D * 4;   // 102.4 MB
    float* hbuf = (float*)p; p += (size_t)N * D * 4;   // 102.4 MB
    int*   deg      = (int*)p;   p += (size_t)N * 4;
    float* dinv     = (float*)p; p += (size_t)N * 4;
    int*   rowstart = (int*)p;   p += (size_t)N * 4;
    int*   cursor   = (int*)p;   p += (size_t)N * 4;
    int*   bsums    = (int*)p;   p += 4096;
    int*   csr      = (int*)p;   p += (size_t)E * 4;   // 6.4 MB

    hipMemsetAsync(deg, 0, (size_t)N * 4, stream);
    hipMemsetAsync(cursor, 0, (size_t)N * 4, stream);

    int ebl = (E + 255) / 256;
    int nbl = (N + 255) / 256;

    count_deg<<<ebl, 256, 0, stream>>>(ei, deg, E);
    deg_inv_k<<<nbl, 256, 0, stream>>>(deg, dinv, N);
    scan1<<<nbl, 256, 0, stream>>>(deg, rowstart, bsums, N);
    scan2<<<1, 1, 0, stream>>>(bsums, nbl);
    scan3<<<nbl, 256, 0, stream>>>(rowstart, bsums, N);
    fill_csr<<<ebl, 256, 0, stream>>>(ei, rowstart, cursor, csr, E);

    // conv1: h1 = relu(mean(x) @ W1l + x @ W1r + b1)
    agg_k<<<N / 4, 256, 0, stream>>>(x, csr, rowstart, deg, agg);
    conv_k<<<N / NPB, 256, 0, stream>>>(agg, dinv, x, W1l, W1r, b1, hbuf);
    // conv2: h2 = relu(mean(h1) @ W2l + h1 @ W2r + b2)  (written in place over agg)
    agg_k<<<N / 4, 256, 0, stream>>>(hbuf, csr, rowstart, deg, agg);
    conv_k<<<N / NPB, 256, 0, stream>>>(agg, dinv, hbuf, W2l, W2r, b2, agg);
    // head: out = h2 @ W3 + b3
    lin_k<<<N / NPB, 256, 0, stream>>>(agg, W3, b3, out);
}

// Round 2
// 1191.778 us; speedup vs baseline: 2.1250x; 2.1250x over previous
//
#include <hip/hip_runtime.h>
#include <hip/hip_bf16.h>
#include <cstdint>
#include <cstddef>

#define N_NODES 100000
#define D 256
#define NSTRIP 6250   // N_NODES / 16 row-strips for MFMA kernels

typedef __attribute__((ext_vector_type(8))) short short8;   // 8 bf16 = 4 VGPRs
typedef __attribute__((ext_vector_type(4))) float f32x4;

__device__ __forceinline__ float bf2f_lo(unsigned int u) {
    unsigned int x = u << 16;
    float f; __builtin_memcpy(&f, &x, 4); return f;
}
__device__ __forceinline__ float bf2f_hi(unsigned int u) {
    unsigned int x = u & 0xFFFF0000u;
    float f; __builtin_memcpy(&f, &x, 4); return f;
}
__device__ __forceinline__ unsigned short f2bf(float f) {
    unsigned int x; __builtin_memcpy(&x, &f, 4);
    unsigned int r = (x + 0x7FFFu + ((x >> 16) & 1u)) >> 16;   // RNE
    return (unsigned short)r;
}

// ---------------- CSR build ----------------

__global__ __launch_bounds__(256) void count_deg(const int* __restrict__ ei,
                                                 int* __restrict__ deg, int E) {
    int e = blockIdx.x * 256 + threadIdx.x;
    if (e < E) atomicAdd(&deg[ei[E + e]], 1);
}

__global__ __launch_bounds__(256) void deg_inv_k(const int* __restrict__ deg,
                                                 float* __restrict__ dinv, int N) {
    int i = blockIdx.x * 256 + threadIdx.x;
    if (i < N) dinv[i] = 1.0f / fmaxf((float)deg[i], 1.0f);
}

__global__ __launch_bounds__(256) void scan1(const int* __restrict__ deg,
                                             int* __restrict__ rowstart,
                                             int* __restrict__ bsums, int N) {
    __shared__ int s[256];
    int i = blockIdx.x * 256 + threadIdx.x;
    int v = (i < N) ? deg[i] : 0;
    s[threadIdx.x] = v;
    __syncthreads();
    for (int d = 1; d < 256; d <<= 1) {
        int t = (threadIdx.x >= d) ? s[threadIdx.x - d] : 0;
        __syncthreads();
        s[threadIdx.x] += t;
        __syncthreads();
    }
    if (i < N) rowstart[i] = s[threadIdx.x] - v;
    if (threadIdx.x == 255) bsums[blockIdx.x] = s[255];
}

__global__ void scan2(int* bsums, int nb) {
    if (threadIdx.x == 0 && blockIdx.x == 0) {
        int run = 0;
        for (int b = 0; b < nb; b++) { int t = bsums[b]; bsums[b] = run; run += t; }
    }
}

__global__ __launch_bounds__(256) void scan3(int* __restrict__ rowstart,
                                             const int* __restrict__ bsums, int N) {
    int i = blockIdx.x * 256 + threadIdx.x;
    if (i < N) rowstart[i] += bsums[blockIdx.x];
}

__global__ __launch_bounds__(256) void fill_csr(const int* __restrict__ ei,
                                                const int* __restrict__ rowstart,
                                                int* __restrict__ cursor,
                                                int* __restrict__ csr, int E) {
    int e = blockIdx.x * 256 + threadIdx.x;
    if (e < E) {
        int src = ei[e], dst = ei[E + e];
        int slot = atomicAdd(&cursor[dst], 1);
        csr[rowstart[dst] + slot] = src;
    }
}

// ---------------- dtype prep ----------------

// f32 -> bf16, 4 elems/thread
__global__ __launch_bounds__(256) void cvt_bf16(const float* __restrict__ src,
                                                unsigned short* __restrict__ dst,
                                                size_t n4) {
    size_t i = (size_t)blockIdx.x * 256 + threadIdx.x;
    if (i >= n4) return;
    float4 v = *(const float4*)(src + i * 4);
    ushort4 o;
    o.x = f2bf(v.x); o.y = f2bf(v.y); o.z = f2bf(v.z); o.w = f2bf(v.w);
    *(ushort4*)(dst + i * 4) = o;
}

// W[k][n] f32 -> WT[n][k] bf16  (256x256)
__global__ __launch_bounds__(256) void wt_prep(const float* __restrict__ W,
                                               unsigned short* __restrict__ WT) {
    int k = blockIdx.x;          // 0..255
    int n = threadIdx.x;         // 0..255
    WT[n * D + k] = f2bf(W[k * D + n]);
}

// ---------------- aggregation: half-wave (32 lanes) per node, bf16 in/out ----------------
// lane holds 8 consecutive cols (16B loads). Accumulate fp32, scale by dinv, store bf16.

__global__ __launch_bounds__(256) void agg_bf16(const unsigned short* __restrict__ Xb,
                                                const int* __restrict__ csr,
                                                const int* __restrict__ rowstart,
                                                const int* __restrict__ deg,
                                                const float* __restrict__ dinv,
                                                unsigned short* __restrict__ outb) {
    int node = blockIdx.x * 8 + (threadIdx.x >> 5);   // grid = N/8 exactly
    int l = threadIdx.x & 31;
    int start = rowstart[node];
    int cnt = deg[node];
    float acc[8];
#pragma unroll
    for (int i = 0; i < 8; i++) acc[i] = 0.f;
    int j = 0;
    for (; j + 2 <= cnt; j += 2) {
        int s0 = csr[start + j];
        int s1 = csr[start + j + 1];
        uint4 v0 = *(const uint4*)(Xb + (size_t)s0 * D + l * 8);
        uint4 v1 = *(const uint4*)(Xb + (size_t)s1 * D + l * 8);
        acc[0] += bf2f_lo(v0.x) + bf2f_lo(v1.x);
        acc[1] += bf2f_hi(v0.x) + bf2f_hi(v1.x);
        acc[2] += bf2f_lo(v0.y) + bf2f_lo(v1.y);
        acc[3] += bf2f_hi(v0.y) + bf2f_hi(v1.y);
        acc[4] += bf2f_lo(v0.z) + bf2f_lo(v1.z);
        acc[5] += bf2f_hi(v0.z) + bf2f_hi(v1.z);
        acc[6] += bf2f_lo(v0.w) + bf2f_lo(v1.w);
        acc[7] += bf2f_hi(v0.w) + bf2f_hi(v1.w);
    }
    if (j < cnt) {
        int s0 = csr[start + j];
        uint4 v0 = *(const uint4*)(Xb + (size_t)s0 * D + l * 8);
        acc[0] += bf2f_lo(v0.x); acc[1] += bf2f_hi(v0.x);
        acc[2] += bf2f_lo(v0.y); acc[3] += bf2f_hi(v0.y);
        acc[4] += bf2f_lo(v0.z); acc[5] += bf2f_hi(v0.z);
        acc[6] += bf2f_lo(v0.w); acc[7] += bf2f_hi(v0.w);
    }
    float s = dinv[node];
    uint4 o;
    o.x = (unsigned int)f2bf(acc[0] * s) | ((unsigned int)f2bf(acc[1] * s) << 16);
    o.y = (unsigned int)f2bf(acc[2] * s) | ((unsigned int)f2bf(acc[3] * s) << 16);
    o.z = (unsigned int)f2bf(acc[4] * s) | ((unsigned int)f2bf(acc[5] * s) << 16);
    o.w = (unsigned int)f2bf(acc[6] * s) | ((unsigned int)f2bf(acc[7] * s) << 16);
    *(uint4*)(outb + (size_t)node * D + l * 8) = o;
}

// ---------------- fused SAGE conv via MFMA ----------------
// out = relu(A1 @ W1^T_T + A2 @ W2^T_T + b), all operands bf16, acc fp32.
// One wave per 16-row strip; A frags preloaded (2 x 8 chunks x 16B); B frags
// streamed from L2 (WT is [N][K] so frag loads are contiguous 16B).

__global__ __launch_bounds__(256) void conv_mfma(const unsigned short* __restrict__ A1,
                                                 const unsigned short* __restrict__ A2,
                                                 const unsigned short* __restrict__ WT1,
                                                 const unsigned short* __restrict__ WT2,
                                                 const float* __restrict__ bias,
                                                 unsigned short* __restrict__ outb) {
    int wid = blockIdx.x * 4 + (threadIdx.x >> 6);
    if (wid >= NSTRIP) return;
    int lane = threadIdx.x & 63;
    int m = lane & 15, q = lane >> 4;
    int row0 = wid * 16;

    const short8* pa1 = (const short8*)(A1 + (size_t)(row0 + m) * D + q * 8);
    const short8* pa2 = (const short8*)(A2 + (size_t)(row0 + m) * D + q * 8);
    short8 a1[8], a2[8];
#pragma unroll
    for (int c = 0; c < 8; c++) { a1[c] = pa1[c * 4]; a2[c] = pa2[c * 4]; }

    for (int nt = 0; nt < 16; nt++) {
        int col0 = nt * 16;
        const short8* pb1 = (const short8*)(WT1 + (size_t)(col0 + m) * D + q * 8);
        const short8* pb2 = (const short8*)(WT2 + (size_t)(col0 + m) * D + q * 8);
        f32x4 acc = {0.f, 0.f, 0.f, 0.f};
#pragma unroll
        for (int c = 0; c < 8; c++) {
            acc = __builtin_amdgcn_mfma_f32_16x16x32_bf16(a1[c], pb1[c * 4], acc, 0, 0, 0);
            acc = __builtin_amdgcn_mfma_f32_16x16x32_bf16(a2[c], pb2[c * 4], acc, 0, 0, 0);
        }
        float b = bias[col0 + m];
#pragma unroll
        for (int r = 0; r < 4; r++) {
            int row = row0 + q * 4 + r;                 // C/D: col=lane&15, row=quad*4+reg
            float v = acc[r] + b;
            v = fmaxf(v, 0.f);
            outb[(size_t)row * D + col0 + m] = f2bf(v);
        }
    }
}

// final linear: out_f32 = A @ WT^T + b (no relu)
__global__ __launch_bounds__(256) void lin_mfma(const unsigned short* __restrict__ A,
                                                const unsigned short* __restrict__ WT,
                                                const float* __restrict__ bias,
                                                float* __restrict__ out) {
    int wid = blockIdx.x * 4 + (threadIdx.x >> 6);
    if (wid >= NSTRIP) return;
    int lane = threadIdx.x & 63;
    int m = lane & 15, q = lane >> 4;
    int row0 = wid * 16;

    const short8* pa = (const short8*)(A + (size_t)(row0 + m) * D + q * 8);
    short8 a[8];
#pragma unroll
    for (int c = 0; c < 8; c++) a[c] = pa[c * 4];

    for (int nt = 0; nt < 16; nt++) {
        int col0 = nt * 16;
        const short8* pb = (const short8*)(WT + (size_t)(col0 + m) * D + q * 8);
        f32x4 acc = {0.f, 0.f, 0.f, 0.f};
#pragma unroll
        for (int c = 0; c < 8; c++)
            acc = __builtin_amdgcn_mfma_f32_16x16x32_bf16(a[c], pb[c * 4], acc, 0, 0, 0);
        float b = bias[col0 + m];
#pragma unroll
        for (int r = 0; r < 4; r++) {
            int row = row0 + q * 4 + r;
            out[(size_t)row * D + col0 + m] = acc[r] + b;
        }
    }
}

// ---------------- launch ----------------

extern "C" void kernel_launch(void* const* d_in, const int* in_sizes, int n_in,
                              void* d_out, int out_size, void* d_ws, size_t ws_size,
                              hipStream_t stream) {
    const float* x   = (const float*)d_in[0];
    const int*   ei  = (const int*)d_in[1];
    const float* W1l = (const float*)d_in[2];
    const float* b1  = (const float*)d_in[3];
    const float* W1r = (const float*)d_in[4];
    const float* W2l = (const float*)d_in[5];
    const float* b2  = (const float*)d_in[6];
    const float* W2r = (const float*)d_in[7];
    const float* W3  = (const float*)d_in[8];
    const float* b3  = (const float*)d_in[9];
    float* out = (float*)d_out;

    const int N = N_NODES;
    const int E = in_sizes[1] / 2;
    const size_t FB = (size_t)N * D * sizeof(unsigned short);   // 51.2 MB

    char* p = (char*)d_ws;
    unsigned short* B1 = (unsigned short*)p; p += FB;   // xb, then h2b
    unsigned short* B2 = (unsigned short*)p; p += FB;   // a1b, then a2b
    unsigned short* B3 = (unsigned short*)p; p += FB;   // h1b
    unsigned short* WT1l = (unsigned short*)p; p += (size_t)D * D * 2;
    unsigned short* WT1r = (unsigned short*)p; p += (size_t)D * D * 2;
    unsigned short* WT2l = (unsigned short*)p; p += (size_t)D * D * 2;
    unsigned short* WT2r = (unsigned short*)p; p += (size_t)D * D * 2;
    unsigned short* WT3  = (unsigned short*)p; p += (size_t)D * D * 2;
    int*   deg      = (int*)p;   p += (size_t)N * 4;
    float* dinv     = (float*)p; p += (size_t)N * 4;
    int*   rowstart = (int*)p;   p += (size_t)N * 4;
    int*   cursor   = (int*)p;   p += (size_t)N * 4;
    int*   bsums    = (int*)p;   p += 4096;
    int*   csr      = (int*)p;   p += (size_t)E * 4;

    hipMemsetAsync(deg, 0, (size_t)N * 4, stream);
    hipMemsetAsync(cursor, 0, (size_t)N * 4, stream);

    int ebl = (E + 255) / 256;
    int nbl = (N + 255) / 256;

    // CSR
    count_deg<<<ebl, 256, 0, stream>>>(ei, deg, E);
    deg_inv_k<<<nbl, 256, 0, stream>>>(deg, dinv, N);
    scan1<<<nbl, 256, 0, stream>>>(deg, rowstart, bsums, N);
    scan2<<<1, 1, 0, stream>>>(bsums, nbl);
    scan3<<<nbl, 256, 0, stream>>>(rowstart, bsums, N);
    fill_csr<<<ebl, 256, 0, stream>>>(ei, rowstart, cursor, csr, E);

    // dtype prep
    cvt_bf16<<<(int)(((size_t)N * D / 4 + 255) / 256), 256, 0, stream>>>(x, B1, (size_t)N * D / 4);
    wt_prep<<<D, 256, 0, stream>>>(W1l, WT1l);
    wt_prep<<<D, 256, 0, stream>>>(W1r, WT1r);
    wt_prep<<<D, 256, 0, stream>>>(W2l, WT2l);
    wt_prep<<<D, 256, 0, stream>>>(W2r, WT2r);
    wt_prep<<<D, 256, 0, stream>>>(W3,  WT3);

    int gmm = (NSTRIP + 3) / 4;   // 1563 blocks of 4 waves

    // conv1: h1 = relu(mean(x)@W1l + x@W1r + b1)
    agg_bf16<<<N / 8, 256, 0, stream>>>(B1, csr, rowstart, deg, dinv, B2);
    conv_mfma<<<gmm, 256, 0, stream>>>(B2, B1, WT1l, WT1r, b1, B3);
    // conv2: h2 = relu(mean(h1)@W2l + h1@W2r + b2)
    agg_bf16<<<N / 8, 256, 0, stream>>>(B3, csr, rowstart, deg, dinv, B2);
    conv_mfma<<<gmm, 256, 0, stream>>>(B2, B3, WT2l, WT2r, b2, B1);
    // head
    lin_mfma<<<gmm, 256, 0, stream>>>(B1, WT3, b3, out);
}

// Round 3
// 764.244 us; speedup vs baseline: 3.3138x; 1.5594x over previous
//
#include <hip/hip_runtime.h>
#include <hip/hip_bf16.h>
#include <cstdint>
#include <cstddef>

#define N_NODES 100000
#define N_PAD   100096   // 782 * 128, M padded to block tile
#define D 256

typedef __attribute__((ext_vector_type(8))) short short8;   // 8 bf16 = 4 VGPRs
typedef __attribute__((ext_vector_type(4))) float f32x4;

__device__ __forceinline__ float bf2f_lo(unsigned int u) {
    unsigned int x = u << 16;
    float f; __builtin_memcpy(&f, &x, 4); return f;
}
__device__ __forceinline__ float bf2f_hi(unsigned int u) {
    unsigned int x = u & 0xFFFF0000u;
    float f; __builtin_memcpy(&f, &x, 4); return f;
}
__device__ __forceinline__ unsigned short f2bf(float f) {
    unsigned int x; __builtin_memcpy(&x, &f, 4);
    unsigned int r = (x + 0x7FFFu + ((x >> 16) & 1u)) >> 16;   // RNE
    return (unsigned short)r;
}

// ---------------- CSR build ----------------

__global__ __launch_bounds__(256) void count_deg(const int* __restrict__ ei,
                                                 int* __restrict__ deg, int E) {
    int e = blockIdx.x * 256 + threadIdx.x;
    if (e < E) atomicAdd(&deg[ei[E + e]], 1);
}

__global__ __launch_bounds__(256) void deg_inv_k(const int* __restrict__ deg,
                                                 float* __restrict__ dinv, int N) {
    int i = blockIdx.x * 256 + threadIdx.x;
    if (i < N) dinv[i] = 1.0f / fmaxf((float)deg[i], 1.0f);
}

__global__ __launch_bounds__(256) void scan1(const int* __restrict__ deg,
                                             int* __restrict__ rowstart,
                                             int* __restrict__ bsums, int N) {
    __shared__ int s[256];
    int i = blockIdx.x * 256 + threadIdx.x;
    int v = (i < N) ? deg[i] : 0;
    s[threadIdx.x] = v;
    __syncthreads();
    for (int d = 1; d < 256; d <<= 1) {
        int t = (threadIdx.x >= d) ? s[threadIdx.x - d] : 0;
        __syncthreads();
        s[threadIdx.x] += t;
        __syncthreads();
    }
    if (i < N) rowstart[i] = s[threadIdx.x] - v;
    if (threadIdx.x == 255) bsums[blockIdx.x] = s[255];
}

__global__ void scan2(int* bsums, int nb) {
    if (threadIdx.x == 0 && blockIdx.x == 0) {
        int run = 0;
        for (int b = 0; b < nb; b++) { int t = bsums[b]; bsums[b] = run; run += t; }
    }
}

__global__ __launch_bounds__(256) void scan3(int* __restrict__ rowstart,
                                             const int* __restrict__ bsums, int N) {
    int i = blockIdx.x * 256 + threadIdx.x;
    if (i < N) rowstart[i] += bsums[blockIdx.x];
}

__global__ __launch_bounds__(256) void fill_csr(const int* __restrict__ ei,
                                                const int* __restrict__ rowstart,
                                                int* __restrict__ cursor,
                                                int* __restrict__ csr, int E) {
    int e = blockIdx.x * 256 + threadIdx.x;
    if (e < E) {
        int src = ei[e], dst = ei[E + e];
        int slot = atomicAdd(&cursor[dst], 1);
        csr[rowstart[dst] + slot] = src;
    }
}

// ---------------- dtype prep ----------------

__global__ __launch_bounds__(256) void cvt_bf16(const float* __restrict__ src,
                                                unsigned short* __restrict__ dst,
                                                size_t n4) {
    size_t i = (size_t)blockIdx.x * 256 + threadIdx.x;
    if (i >= n4) return;
    float4 v = *(const float4*)(src + i * 4);
    ushort4 o;
    o.x = f2bf(v.x); o.y = f2bf(v.y); o.z = f2bf(v.z); o.w = f2bf(v.w);
    *(ushort4*)(dst + i * 4) = o;
}

// W [K=256][N=256] f32 -> fragment-ordered bf16:
// Wf[(kc*16 + ct)*64 + lane] = 8 bf16: B[k = kc*32 + (lane>>4)*8 + j][n = ct*16 + (lane&15)]
// One block per (kc, ct) group, 64 threads = lanes.
__global__ __launch_bounds__(64) void wfrag_prep(const float* __restrict__ W,
                                                 unsigned short* __restrict__ Wf) {
    int g = blockIdx.x;              // 0..127: kc*16 + ct
    int lane = threadIdx.x;
    int m = lane & 15, q = lane >> 4;
    int ct = g & 15, kc = g >> 4;
    int n = ct * 16 + m;
    int k0 = kc * 32 + q * 8;
    unsigned short v[8];
#pragma unroll
    for (int j = 0; j < 8; j++) v[j] = f2bf(W[(size_t)(k0 + j) * D + n]);
    *(short8*)(Wf + ((size_t)g * 64 + lane) * 8) = *(short8*)v;
}

// ---------------- aggregation: half-wave (32 lanes) per node, bf16 in/out ----------------

__global__ __launch_bounds__(256) void agg_bf16(const unsigned short* __restrict__ Xb,
                                                const int* __restrict__ csr,
                                                const int* __restrict__ rowstart,
                                                const int* __restrict__ deg,
                                                const float* __restrict__ dinv,
                                                unsigned short* __restrict__ outb) {
    int node = blockIdx.x * 8 + (threadIdx.x >> 5);
    int l = threadIdx.x & 31;
    int start = rowstart[node];
    int cnt = deg[node];
    float acc[8];
#pragma unroll
    for (int i = 0; i < 8; i++) acc[i] = 0.f;
    int j = 0;
    for (; j + 2 <= cnt; j += 2) {
        int s0 = csr[start + j];
        int s1 = csr[start + j + 1];
        uint4 v0 = *(const uint4*)(Xb + (size_t)s0 * D + l * 8);
        uint4 v1 = *(const uint4*)(Xb + (size_t)s1 * D + l * 8);
        acc[0] += bf2f_lo(v0.x) + bf2f_lo(v1.x);
        acc[1] += bf2f_hi(v0.x) + bf2f_hi(v1.x);
        acc[2] += bf2f_lo(v0.y) + bf2f_lo(v1.y);
        acc[3] += bf2f_hi(v0.y) + bf2f_hi(v1.y);
        acc[4] += bf2f_lo(v0.z) + bf2f_lo(v1.z);
        acc[5] += bf2f_hi(v0.z) + bf2f_hi(v1.z);
        acc[6] += bf2f_lo(v0.w) + bf2f_lo(v1.w);
        acc[7] += bf2f_hi(v0.w) + bf2f_hi(v1.w);
    }
    if (j < cnt) {
        int s0 = csr[start + j];
        uint4 v0 = *(const uint4*)(Xb + (size_t)s0 * D + l * 8);
        acc[0] += bf2f_lo(v0.x); acc[1] += bf2f_hi(v0.x);
        acc[2] += bf2f_lo(v0.y); acc[3] += bf2f_hi(v0.y);
        acc[4] += bf2f_lo(v0.z); acc[5] += bf2f_hi(v0.z);
        acc[6] += bf2f_lo(v0.w); acc[7] += bf2f_hi(v0.w);
    }
    float s = dinv[node];
    uint4 o;
    o.x = (unsigned int)f2bf(acc[0] * s) | ((unsigned int)f2bf(acc[1] * s) << 16);
    o.y = (unsigned int)f2bf(acc[2] * s) | ((unsigned int)f2bf(acc[3] * s) << 16);
    o.z = (unsigned int)f2bf(acc[4] * s) | ((unsigned int)f2bf(acc[5] * s) << 16);
    o.w = (unsigned int)f2bf(acc[6] * s) | ((unsigned int)f2bf(acc[7] * s) << 16);
    *(uint4*)(outb + (size_t)node * D + l * 8) = o;
}

// ---------------- block-tiled fused SAGE conv ----------------
// out = relu([Am | X] @ Wf + b): M-tile 128 (4 waves x 32 rows), N=256, K=512.
// Wf is fragment-ordered; each K-chunk (K=32, 16 KB) staged to LDS via
// global_load_lds (double-buffered), reused by all 4 waves. 2 strips x 16
// col-tiles = 32 independent MFMA chains per wave.

#define STAGE(kc, buf)                                                          \
    {                                                                           \
        const unsigned short* gk = Wf + (size_t)(kc) * 8192;                    \
        _Pragma("unroll")                                                       \
        for (int i_ = 0; i_ < 4; i_++) {                                        \
            __builtin_amdgcn_global_load_lds(                                   \
                (const __attribute__((address_space(1))) unsigned int*)         \
                    (gk + (i_ * 256 + tid) * 8),                                \
                (__attribute__((address_space(3))) unsigned int*)               \
                    (&lds[buf][(i_ * 256 + (tid & 192)) * 8]),                  \
                16, 0, 0);                                                      \
        }                                                                       \
    }

__global__ __launch_bounds__(256) void conv_mfma(const unsigned short* __restrict__ Am,
                                                 const unsigned short* __restrict__ X,
                                                 const unsigned short* __restrict__ Wf,
                                                 const float* __restrict__ bias,
                                                 unsigned short* __restrict__ outb) {
    __shared__ unsigned short lds[2][8192];   // 2 x 16 KB
    int tid = threadIdx.x;
    int lane = tid & 63;
    int m = lane & 15, q = lane >> 4;
    int row0 = blockIdx.x * 128 + (tid >> 6) * 32;

    f32x4 acc[2][16];
#pragma unroll
    for (int s = 0; s < 2; s++)
#pragma unroll
        for (int ct = 0; ct < 16; ct++) acc[s][ct] = (f32x4){0.f, 0.f, 0.f, 0.f};

    STAGE(0, 0);
    for (int kc = 0; kc < 16; kc++) {
        __syncthreads();                       // stage(kc) landed; buf free
        if (kc < 15) STAGE(kc + 1, (kc + 1) & 1);
        const unsigned short* Asrc = (kc < 8) ? Am : X;
        int koff = (kc & 7) * 32 + q * 8;
        short8 a0 = *(const short8*)(Asrc + (size_t)(row0 + m) * D + koff);
        short8 a1 = *(const short8*)(Asrc + (size_t)(row0 + 16 + m) * D + koff);
        const unsigned short* lb = lds[kc & 1];
#pragma unroll
        for (int ct = 0; ct < 16; ct++) {
            short8 b = *(const short8*)(lb + ((size_t)ct * 64 + lane) * 8);
            acc[0][ct] = __builtin_amdgcn_mfma_f32_16x16x32_bf16(a0, b, acc[0][ct], 0, 0, 0);
            acc[1][ct] = __builtin_amdgcn_mfma_f32_16x16x32_bf16(a1, b, acc[1][ct], 0, 0, 0);
        }
    }
#pragma unroll
    for (int s = 0; s < 2; s++)
#pragma unroll
        for (int ct = 0; ct < 16; ct++) {
            float bb = bias[ct * 16 + m];
#pragma unroll
            for (int r = 0; r < 4; r++) {
                int row = row0 + s * 16 + q * 4 + r;
                float v = acc[s][ct][r] + bb;
                outb[(size_t)row * D + ct * 16 + m] = f2bf(fmaxf(v, 0.f));
            }
        }
}

// final linear: out = A @ Wf + b, f32 out, store-guarded to N_NODES, no relu
__global__ __launch_bounds__(256) void lin_mfma(const unsigned short* __restrict__ A,
                                                const unsigned short* __restrict__ Wf,
                                                const float* __restrict__ bias,
                                                float* __restrict__ out) {
    __shared__ unsigned short lds[2][8192];
    int tid = threadIdx.x;
    int lane = tid & 63;
    int m = lane & 15, q = lane >> 4;
    int row0 = blockIdx.x * 128 + (tid >> 6) * 32;

    f32x4 acc[2][16];
#pragma unroll
    for (int s = 0; s < 2; s++)
#pragma unroll
        for (int ct = 0; ct < 16; ct++) acc[s][ct] = (f32x4){0.f, 0.f, 0.f, 0.f};

    STAGE(0, 0);
    for (int kc = 0; kc < 8; kc++) {
        __syncthreads();
        if (kc < 7) STAGE(kc + 1, (kc + 1) & 1);
        int koff = kc * 32 + q * 8;
        short8 a0 = *(const short8*)(A + (size_t)(row0 + m) * D + koff);
        short8 a1 = *(const short8*)(A + (size_t)(row0 + 16 + m) * D + koff);
        const unsigned short* lb = lds[kc & 1];
#pragma unroll
        for (int ct = 0; ct < 16; ct++) {
            short8 b = *(const short8*)(lb + ((size_t)ct * 64 + lane) * 8);
            acc[0][ct] = __builtin_amdgcn_mfma_f32_16x16x32_bf16(a0, b, acc[0][ct], 0, 0, 0);
            acc[1][ct] = __builtin_amdgcn_mfma_f32_16x16x32_bf16(a1, b, acc[1][ct], 0, 0, 0);
        }
    }
#pragma unroll
    for (int s = 0; s < 2; s++)
#pragma unroll
        for (int ct = 0; ct < 16; ct++) {
            float bb = bias[ct * 16 + m];
#pragma unroll
            for (int r = 0; r < 4; r++) {
                int row = row0 + s * 16 + q * 4 + r;
                if (row < N_NODES)
                    out[(size_t)row * D + ct * 16 + m] = acc[s][ct][r] + bb;
            }
        }
}

// ---------------- launch ----------------

extern "C" void kernel_launch(void* const* d_in, const int* in_sizes, int n_in,
                              void* d_out, int out_size, void* d_ws, size_t ws_size,
                              hipStream_t stream) {
    const float* x   = (const float*)d_in[0];
    const int*   ei  = (const int*)d_in[1];
    const float* W1l = (const float*)d_in[2];
    const float* b1  = (const float*)d_in[3];
    const float* W1r = (const float*)d_in[4];
    const float* W2l = (const float*)d_in[5];
    const float* b2  = (const float*)d_in[6];
    const float* W2r = (const float*)d_in[7];
    const float* W3  = (const float*)d_in[8];
    const float* b3  = (const float*)d_in[9];
    float* out = (float*)d_out;

    const int N = N_NODES;
    const int E = in_sizes[1] / 2;
    const size_t FB = (size_t)N_PAD * D * sizeof(unsigned short);   // 51.25 MB
    const size_t WFRAG = (size_t)128 * 64 * 8;   // shorts per 256-K half

    char* p = (char*)d_ws;
    unsigned short* B1 = (unsigned short*)p; p += FB;   // xb, then conv2 out (h2)
    unsigned short* B2 = (unsigned short*)p; p += FB;   // agg out (mean)
    unsigned short* B3 = (unsigned short*)p; p += FB;   // conv1 out (h1)
    unsigned short* Wf1 = (unsigned short*)p; p += WFRAG * 2 * 2;   // [W1l | W1r] frag, 256 KB
    unsigned short* Wf2 = (unsigned short*)p; p += WFRAG * 2 * 2;
    unsigned short* Wf3 = (unsigned short*)p; p += WFRAG * 2;       // 128 KB
    int*   deg      = (int*)p;   p += (size_t)N * 4;
    float* dinv     = (float*)p; p += (size_t)N * 4;
    int*   rowstart = (int*)p;   p += (size_t)N * 4;
    int*   cursor   = (int*)p;   p += (size_t)N * 4;
    int*   bsums    = (int*)p;   p += 4096;
    int*   csr      = (int*)p;   p += (size_t)E * 4;

    hipMemsetAsync(deg, 0, (size_t)N * 4, stream);
    hipMemsetAsync(cursor, 0, (size_t)N * 4, stream);

    int ebl = (E + 255) / 256;
    int nbl = (N + 255) / 256;

    // CSR
    count_deg<<<ebl, 256, 0, stream>>>(ei, deg, E);
    deg_inv_k<<<nbl, 256, 0, stream>>>(deg, dinv, N);
    scan1<<<nbl, 256, 0, stream>>>(deg, rowstart, bsums, N);
    scan2<<<1, 1, 0, stream>>>(bsums, nbl);
    scan3<<<nbl, 256, 0, stream>>>(rowstart, bsums, N);
    fill_csr<<<ebl, 256, 0, stream>>>(ei, rowstart, cursor, csr, E);

    // dtype prep: x -> bf16; weights -> fragment order (K 0..255 = lin_l/mean
    // path, K 256..511 = lin_r/x path)
    cvt_bf16<<<(int)(((size_t)N * D / 4 + 255) / 256), 256, 0, stream>>>(x, B1, (size_t)N * D / 4);
    wfrag_prep<<<128, 64, 0, stream>>>(W1l, Wf1);
    wfrag_prep<<<128, 64, 0, stream>>>(W1r, Wf1 + WFRAG);
    wfrag_prep<<<128, 64, 0, stream>>>(W2l, Wf2);
    wfrag_prep<<<128, 64, 0, stream>>>(W2r, Wf2 + WFRAG);
    wfrag_prep<<<128, 64, 0, stream>>>(W3,  Wf3);

    const int gmm = N_PAD / 128;   // 782 blocks

    // conv1: h1 = relu(mean(x)@W1l + x@W1r + b1)
    agg_bf16<<<N / 8, 256, 0, stream>>>(B1, csr, rowstart, deg, dinv, B2);
    conv_mfma<<<gmm, 256, 0, stream>>>(B2, B1, Wf1, b1, B3);
    // conv2: h2 = relu(mean(h1)@W2l + h1@W2r + b2)
    agg_bf16<<<N / 8, 256, 0, stream>>>(B3, csr, rowstart, deg, dinv, B2);
    conv_mfma<<<gmm, 256, 0, stream>>>(B2, B3, Wf2, b2, B1);
    // head
    lin_mfma<<<gmm, 256, 0, stream>>>(B1, Wf3, b3, out);
}

// Round 4
// 718.842 us; speedup vs baseline: 3.5231x; 1.0632x over previous
//
#include <hip/hip_runtime.h>
#include <hip/hip_bf16.h>
#include <cstdint>
#include <cstddef>

#define N_NODES 100000
#define N_PAD   100096   // 782 * 128, M padded to block tile
#define D 256

typedef __attribute__((ext_vector_type(8))) short short8;   // 8 bf16 = 4 VGPRs
typedef __attribute__((ext_vector_type(4))) float f32x4;

__device__ __forceinline__ float bf2f_lo(unsigned int u) {
    unsigned int x = u << 16;
    float f; __builtin_memcpy(&f, &x, 4); return f;
}
__device__ __forceinline__ float bf2f_hi(unsigned int u) {
    unsigned int x = u & 0xFFFF0000u;
    float f; __builtin_memcpy(&f, &x, 4); return f;
}
__device__ __forceinline__ unsigned short f2bf(float f) {
    unsigned int x; __builtin_memcpy(&x, &f, 4);
    unsigned int r = (x + 0x7FFFu + ((x >> 16) & 1u)) >> 16;   // RNE
    return (unsigned short)r;
}

// ---------------- CSR build ----------------

__global__ __launch_bounds__(256) void count_deg(const int* __restrict__ ei,
                                                 int* __restrict__ deg, int E) {
    int e = blockIdx.x * 256 + threadIdx.x;
    if (e < E) atomicAdd(&deg[ei[E + e]], 1);
}

__global__ __launch_bounds__(256) void deg_inv_k(const int* __restrict__ deg,
                                                 float* __restrict__ dinv, int N) {
    int i = blockIdx.x * 256 + threadIdx.x;
    if (i < N) dinv[i] = 1.0f / fmaxf((float)deg[i], 1.0f);
}

__global__ __launch_bounds__(256) void scan1(const int* __restrict__ deg,
                                             int* __restrict__ rowstart,
                                             int* __restrict__ bsums, int N) {
    __shared__ int s[256];
    int i = blockIdx.x * 256 + threadIdx.x;
    int v = (i < N) ? deg[i] : 0;
    s[threadIdx.x] = v;
    __syncthreads();
    for (int d = 1; d < 256; d <<= 1) {
        int t = (threadIdx.x >= d) ? s[threadIdx.x - d] : 0;
        __syncthreads();
        s[threadIdx.x] += t;
        __syncthreads();
    }
    if (i < N) rowstart[i] = s[threadIdx.x] - v;
    if (threadIdx.x == 255) bsums[blockIdx.x] = s[255];
}

// parallel one-block exclusive scan of bsums (nb <= 512), 256 threads x 2 elems
__global__ __launch_bounds__(256) void scan2p(int* __restrict__ bsums, int nb) {
    __shared__ int s[256];
    int t = threadIdx.x;
    int base = t * 2;
    int v0 = (base < nb) ? bsums[base] : 0;
    int v1 = (base + 1 < nb) ? bsums[base + 1] : 0;
    int sum = v0 + v1;
    s[t] = sum;
    __syncthreads();
    for (int d = 1; d < 256; d <<= 1) {
        int tv = (t >= d) ? s[t - d] : 0;
        __syncthreads();
        s[t] += tv;
        __syncthreads();
    }
    int excl = s[t] - sum;
    if (base < nb) bsums[base] = excl;
    if (base + 1 < nb) bsums[base + 1] = excl + v0;
}

__global__ __launch_bounds__(256) void scan3(int* __restrict__ rowstart,
                                             const int* __restrict__ bsums, int N) {
    int i = blockIdx.x * 256 + threadIdx.x;
    if (i < N) rowstart[i] += bsums[blockIdx.x];
}

__global__ __launch_bounds__(256) void fill_csr(const int* __restrict__ ei,
                                                const int* __restrict__ rowstart,
                                                int* __restrict__ cursor,
                                                int* __restrict__ csr, int E) {
    int e = blockIdx.x * 256 + threadIdx.x;
    if (e < E) {
        int src = ei[e], dst = ei[E + e];
        int slot = atomicAdd(&cursor[dst], 1);
        csr[rowstart[dst] + slot] = src;
    }
}

// ---------------- dtype prep ----------------

__global__ __launch_bounds__(256) void cvt_bf16(const float* __restrict__ src,
                                                unsigned short* __restrict__ dst,
                                                size_t n4) {
    size_t i = (size_t)blockIdx.x * 256 + threadIdx.x;
    if (i >= n4) return;
    float4 v = *(const float4*)(src + i * 4);
    ushort4 o;
    o.x = f2bf(v.x); o.y = f2bf(v.y); o.z = f2bf(v.z); o.w = f2bf(v.w);
    *(ushort4*)(dst + i * 4) = o;
}

// W [K=256][N=256] f32 -> fragment-ordered bf16, 5 matrices in one launch.
// Wf[(kc*16 + ct)*64 + lane] = 8 bf16: B[k = kc*32 + (lane>>4)*8 + j][n = ct*16 + (lane&15)]
struct WP {
    const float* w[5];
    unsigned short* wf[5];
};
__global__ __launch_bounds__(64) void wfrag_prep(WP wp) {
    const float* __restrict__ W = wp.w[blockIdx.y];
    unsigned short* __restrict__ Wf = wp.wf[blockIdx.y];
    int g = blockIdx.x;              // 0..127: kc*16 + ct
    int lane = threadIdx.x;
    int m = lane & 15, q = lane >> 4;
    int ct = g & 15, kc = g >> 4;
    int n = ct * 16 + m;
    int k0 = kc * 32 + q * 8;
    unsigned short v[8];
#pragma unroll
    for (int j = 0; j < 8; j++) v[j] = f2bf(W[(size_t)(k0 + j) * D + n]);
    *(short8*)(Wf + ((size_t)g * 64 + lane) * 8) = *(short8*)v;
}

// ---------------- aggregation: half-wave (32 lanes) per node, bf16 in/out ----
// 4-deep independent row loads per iteration for memory-level parallelism.

__device__ __forceinline__ void acc8(float* acc, uint4 v) {
    acc[0] += bf2f_lo(v.x); acc[1] += bf2f_hi(v.x);
    acc[2] += bf2f_lo(v.y); acc[3] += bf2f_hi(v.y);
    acc[4] += bf2f_lo(v.z); acc[5] += bf2f_hi(v.z);
    acc[6] += bf2f_lo(v.w); acc[7] += bf2f_hi(v.w);
}

__global__ __launch_bounds__(256) void agg_bf16(const unsigned short* __restrict__ Xb,
                                                const int* __restrict__ csr,
                                                const int* __restrict__ rowstart,
                                                const int* __restrict__ deg,
                                                const float* __restrict__ dinv,
                                                unsigned short* __restrict__ outb) {
    int node = blockIdx.x * 8 + (threadIdx.x >> 5);
    int l = threadIdx.x & 31;
    int start = rowstart[node];
    int cnt = deg[node];
    float acc[8];
#pragma unroll
    for (int i = 0; i < 8; i++) acc[i] = 0.f;
    int j = 0;
    for (; j + 4 <= cnt; j += 4) {
        int s0 = csr[start + j + 0];
        int s1 = csr[start + j + 1];
        int s2 = csr[start + j + 2];
        int s3 = csr[start + j + 3];
        uint4 v0 = *(const uint4*)(Xb + (size_t)s0 * D + l * 8);
        uint4 v1 = *(const uint4*)(Xb + (size_t)s1 * D + l * 8);
        uint4 v2 = *(const uint4*)(Xb + (size_t)s2 * D + l * 8);
        uint4 v3 = *(const uint4*)(Xb + (size_t)s3 * D + l * 8);
        acc8(acc, v0); acc8(acc, v1); acc8(acc, v2); acc8(acc, v3);
    }
    for (; j < cnt; j++) {
        int s0 = csr[start + j];
        uint4 v0 = *(const uint4*)(Xb + (size_t)s0 * D + l * 8);
        acc8(acc, v0);
    }
    float s = dinv[node];
    uint4 o;
    o.x = (unsigned int)f2bf(acc[0] * s) | ((unsigned int)f2bf(acc[1] * s) << 16);
    o.y = (unsigned int)f2bf(acc[2] * s) | ((unsigned int)f2bf(acc[3] * s) << 16);
    o.z = (unsigned int)f2bf(acc[4] * s) | ((unsigned int)f2bf(acc[5] * s) << 16);
    o.w = (unsigned int)f2bf(acc[6] * s) | ((unsigned int)f2bf(acc[7] * s) << 16);
    *(uint4*)(outb + (size_t)node * D + l * 8) = o;
}

// ---------------- block-tiled fused SAGE conv ----------------
// out = relu([Am | X] @ Wf + b): M-tile 128 (4 waves x 32 rows), N=256, K=512.
// Wf is fragment-ordered; each K-chunk (K=32, 16 KB) staged to LDS via
// global_load_lds (double-buffered), reused by all 4 waves.

#define STAGE(kc, buf)                                                          \
    {                                                                           \
        const unsigned short* gk = Wf + (size_t)(kc) * 8192;                    \
        _Pragma("unroll")                                                       \
        for (int i_ = 0; i_ < 4; i_++) {                                        \
            __builtin_amdgcn_global_load_lds(                                   \
                (const __attribute__((address_space(1))) unsigned int*)         \
                    (gk + (i_ * 256 + tid) * 8),                                \
                (__attribute__((address_space(3))) unsigned int*)               \
                    (&lds[buf][(i_ * 256 + (tid & 192)) * 8]),                  \
                16, 0, 0);                                                      \
        }                                                                       \
    }

__global__ __launch_bounds__(256) void conv_mfma(const unsigned short* __restrict__ Am,
                                                 const unsigned short* __restrict__ X,
                                                 const unsigned short* __restrict__ Wf,
                                                 const float* __restrict__ bias,
                                                 unsigned short* __restrict__ outb) {
    __shared__ unsigned short lds[2][8192];   // 2 x 16 KB
    int tid = threadIdx.x;
    int lane = tid & 63;
    int m = lane & 15, q = lane >> 4;
    int row0 = blockIdx.x * 128 + (tid >> 6) * 32;

    f32x4 acc[2][16];
#pragma unroll
    for (int s = 0; s < 2; s++)
#pragma unroll
        for (int ct = 0; ct < 16; ct++) acc[s][ct] = (f32x4){0.f, 0.f, 0.f, 0.f};

    STAGE(0, 0);
    for (int kc = 0; kc < 16; kc++) {
        __syncthreads();                       // stage(kc) landed; buf free
        if (kc < 15) STAGE(kc + 1, (kc + 1) & 1);
        const unsigned short* Asrc = (kc < 8) ? Am : X;
        int koff = (kc & 7) * 32 + q * 8;
        short8 a0 = *(const short8*)(Asrc + (size_t)(row0 + m) * D + koff);
        short8 a1 = *(const short8*)(Asrc + (size_t)(row0 + 16 + m) * D + koff);
        const unsigned short* lb = lds[kc & 1];
#pragma unroll
        for (int ct = 0; ct < 16; ct++) {
            short8 b = *(const short8*)(lb + ((size_t)ct * 64 + lane) * 8);
            acc[0][ct] = __builtin_amdgcn_mfma_f32_16x16x32_bf16(a0, b, acc[0][ct], 0, 0, 0);
            acc[1][ct] = __builtin_amdgcn_mfma_f32_16x16x32_bf16(a1, b, acc[1][ct], 0, 0, 0);
        }
    }
#pragma unroll
    for (int s = 0; s < 2; s++)
#pragma unroll
        for (int ct = 0; ct < 16; ct++) {
            float bb = bias[ct * 16 + m];
#pragma unroll
            for (int r = 0; r < 4; r++) {
                int row = row0 + s * 16 + q * 4 + r;
                float v = acc[s][ct][r] + bb;
                outb[(size_t)row * D + ct * 16 + m] = f2bf(fmaxf(v, 0.f));
            }
        }
}

// final linear: out = A @ Wf + b, f32 out, store-guarded to N_NODES, no relu
__global__ __launch_bounds__(256) void lin_mfma(const unsigned short* __restrict__ A,
                                                const unsigned short* __restrict__ Wf,
                                                const float* __restrict__ bias,
                                                float* __restrict__ out) {
    __shared__ unsigned short lds[2][8192];
    int tid = threadIdx.x;
    int lane = tid & 63;
    int m = lane & 15, q = lane >> 4;
    int row0 = blockIdx.x * 128 + (tid >> 6) * 32;

    f32x4 acc[2][16];
#pragma unroll
    for (int s = 0; s < 2; s++)
#pragma unroll
        for (int ct = 0; ct < 16; ct++) acc[s][ct] = (f32x4){0.f, 0.f, 0.f, 0.f};

    STAGE(0, 0);
    for (int kc = 0; kc < 8; kc++) {
        __syncthreads();
        if (kc < 7) STAGE(kc + 1, (kc + 1) & 1);
        int koff = kc * 32 + q * 8;
        short8 a0 = *(const short8*)(A + (size_t)(row0 + m) * D + koff);
        short8 a1 = *(const short8*)(A + (size_t)(row0 + 16 + m) * D + koff);
        const unsigned short* lb = lds[kc & 1];
#pragma unroll
        for (int ct = 0; ct < 16; ct++) {
            short8 b = *(const short8*)(lb + ((size_t)ct * 64 + lane) * 8);
            acc[0][ct] = __builtin_amdgcn_mfma_f32_16x16x32_bf16(a0, b, acc[0][ct], 0, 0, 0);
            acc[1][ct] = __builtin_amdgcn_mfma_f32_16x16x32_bf16(a1, b, acc[1][ct], 0, 0, 0);
        }
    }
#pragma unroll
    for (int s = 0; s < 2; s++)
#pragma unroll
        for (int ct = 0; ct < 16; ct++) {
            float bb = bias[ct * 16 + m];
#pragma unroll
            for (int r = 0; r < 4; r++) {
                int row = row0 + s * 16 + q * 4 + r;
                if (row < N_NODES)
                    out[(size_t)row * D + ct * 16 + m] = acc[s][ct][r] + bb;
            }
        }
}

// ---------------- launch ----------------

extern "C" void kernel_launch(void* const* d_in, const int* in_sizes, int n_in,
                              void* d_out, int out_size, void* d_ws, size_t ws_size,
                              hipStream_t stream) {
    const float* x   = (const float*)d_in[0];
    const int*   ei  = (const int*)d_in[1];
    const float* W1l = (const float*)d_in[2];
    const float* b1  = (const float*)d_in[3];
    const float* W1r = (const float*)d_in[4];
    const float* W2l = (const float*)d_in[5];
    const float* b2  = (const float*)d_in[6];
    const float* W2r = (const float*)d_in[7];
    const float* W3  = (const float*)d_in[8];
    const float* b3  = (const float*)d_in[9];
    float* out = (float*)d_out;

    const int N = N_NODES;
    const int E = in_sizes[1] / 2;
    const size_t FB = (size_t)N_PAD * D * sizeof(unsigned short);   // 51.25 MB
    const size_t WFRAG = (size_t)128 * 64 * 8;   // shorts per 256-K half

    char* p = (char*)d_ws;
    unsigned short* B1 = (unsigned short*)p; p += FB;   // xb, then conv2 out (h2)
    unsigned short* B2 = (unsigned short*)p; p += FB;   // agg out (mean)
    unsigned short* B3 = (unsigned short*)p; p += FB;   // conv1 out (h1)
    unsigned short* Wf1 = (unsigned short*)p; p += WFRAG * 2 * 2;   // [W1l | W1r] frag
    unsigned short* Wf2 = (unsigned short*)p; p += WFRAG * 2 * 2;
    unsigned short* Wf3 = (unsigned short*)p; p += WFRAG * 2;
    int*   deg      = (int*)p;   p += (size_t)N * 4;
    float* dinv     = (float*)p; p += (size_t)N * 4;
    int*   rowstart = (int*)p;   p += (size_t)N * 4;
    int*   cursor   = (int*)p;   p += (size_t)N * 4;
    int*   bsums    = (int*)p;   p += 4096;
    int*   csr      = (int*)p;   p += (size_t)E * 4;

    hipMemsetAsync(deg, 0, (size_t)N * 4, stream);
    hipMemsetAsync(cursor, 0, (size_t)N * 4, stream);

    int ebl = (E + 255) / 256;
    int nbl = (N + 255) / 256;

    // CSR
    count_deg<<<ebl, 256, 0, stream>>>(ei, deg, E);
    deg_inv_k<<<nbl, 256, 0, stream>>>(deg, dinv, N);
    scan1<<<nbl, 256, 0, stream>>>(deg, rowstart, bsums, N);
    scan2p<<<1, 256, 0, stream>>>(bsums, nbl);
    scan3<<<nbl, 256, 0, stream>>>(rowstart, bsums, N);
    fill_csr<<<ebl, 256, 0, stream>>>(ei, rowstart, cursor, csr, E);

    // dtype prep
    cvt_bf16<<<(int)(((size_t)N * D / 4 + 255) / 256), 256, 0, stream>>>(x, B1, (size_t)N * D / 4);
    WP wp;
    wp.w[0] = W1l; wp.wf[0] = Wf1;
    wp.w[1] = W1r; wp.wf[1] = Wf1 + WFRAG;
    wp.w[2] = W2l; wp.wf[2] = Wf2;
    wp.w[3] = W2r; wp.wf[3] = Wf2 + WFRAG;
    wp.w[4] = W3;  wp.wf[4] = Wf3;
    wfrag_prep<<<dim3(128, 5), 64, 0, stream>>>(wp);

    const int gmm = N_PAD / 128;   // 782 blocks

    // conv1: h1 = relu(mean(x)@W1l + x@W1r + b1)
    agg_bf16<<<N / 8, 256, 0, stream>>>(B1, csr, rowstart, deg, dinv, B2);
    conv_mfma<<<gmm, 256, 0, stream>>>(B2, B1, Wf1, b1, B3);
    // conv2: h2 = relu(mean(h1)@W2l + h1@W2r + b2)
    agg_bf16<<<N / 8, 256, 0, stream>>>(B3, csr, rowstart, deg, dinv, B2);
    conv_mfma<<<gmm, 256, 0, stream>>>(B2, B3, Wf2, b2, B1);
    // head
    lin_mfma<<<gmm, 256, 0, stream>>>(B1, Wf3, b3, out);
}